// Round 3
// baseline (99.924 us; speedup 1.0000x reference)
//
#include <hip/hip_runtime.h>
#include <math.h>

#define NB 1024   // batch
#define NC 64     // input dim
#define NH 128    // hidden dim
#define MAX_IT 500
#define TOLF 6e-3f   // R16: loosened from 1e-3. 1-strong monotonicity bounds
                     // ||x-x*|| < TOL; adds <= 6e-3 to absmax (0.031 now,
                     // 0.169 threshold).

// R19 heavy-ball constants, derived from R16's measured rho=0.77 @ lam=0.23
// => mu=1, L~7.7 (kappa~7.7). Polyak: alpha=4/(sqrt(L)+sqrt(mu))^2 ~ 0.28,
// beta=((sqrt(k)-1)/(sqrt(k)+1))^2 ~ 0.22. Use alpha=0.26 for stability
// margin (converges for L < 2(1+beta)/alpha = 9.4). Predicted rho ~ 0.58.
#define ALPHA_HB 0.26f
#define BETA_HB  0.22f

typedef _Float16 f16x8 __attribute__((ext_vector_type(8)));
typedef float    f32x4 __attribute__((ext_vector_type(4)));
typedef _Float16 h2    __attribute__((ext_vector_type(2)));

#define MFMA(a, b, c) __builtin_amdgcn_mfma_f32_16x16x32_f16((a), (b), (c), 0, 0, 0)

__device__ __forceinline__ unsigned pack_h2(float a, float b) {
    union { h2 h; unsigned u; } cv;
    cv.h.x = (_Float16)a; cv.h.y = (_Float16)b; return cv.u;
}
__device__ __forceinline__ float rcp_fast(float x) {
#if __has_builtin(__builtin_amdgcn_rcpf)
    return __builtin_amdgcn_rcpf(x);
#else
    return 1.0f / x;
#endif
}
// sigmoid + softplus sharing one exp
__device__ __forceinline__ void sigsp(float a, float& sig, float& sp) {
    const float e = __expf(-fabsf(a));
    const float r = rcp_fast(1.0f + e);
    sig = (a >= 0.0f) ? r : e * r;
    sp  = fmaxf(a, 0.0f) + __logf(1.0f + e);
}
__device__ __forceinline__ float sigm(float a) {
    const float e = __expf(-fabsf(a));
    const float r = rcp_fast(1.0f + e);
    return (a >= 0.0f) ? r : e * r;
}
__device__ __forceinline__ float clp(float x) { return fmaxf(x, 0.0f); }

// fragment loaders: 8 fp32 -> f16x8, same element order as the old LDS staging
__device__ __forceinline__ f16x8 ld8(const float* p) {
    const float4 a = ((const float4*)p)[0];
    const float4 b = ((const float4*)p)[1];
    f16x8 r;
    r[0]=(_Float16)a.x; r[1]=(_Float16)a.y; r[2]=(_Float16)a.z; r[3]=(_Float16)a.w;
    r[4]=(_Float16)b.x; r[5]=(_Float16)b.y; r[6]=(_Float16)b.z; r[7]=(_Float16)b.w;
    return r;
}
__device__ __forceinline__ f16x8 ld8_clip(const float* p) {
    const float4 a = ((const float4*)p)[0];
    const float4 b = ((const float4*)p)[1];
    f16x8 r;
    r[0]=(_Float16)clp(a.x); r[1]=(_Float16)clp(a.y); r[2]=(_Float16)clp(a.z); r[3]=(_Float16)clp(a.w);
    r[4]=(_Float16)clp(b.x); r[5]=(_Float16)clp(b.y); r[6]=(_Float16)clp(b.z); r[7]=(_Float16)clp(b.w);
    return r;
}
__device__ __forceinline__ f16x8 ld8_str(const float* p, int stride) {
    f16x8 r;
    #pragma unroll
    for (int j = 0; j < 8; ++j) r[j] = (_Float16)p[j * stride];
    return r;
}
__device__ __forceinline__ f16x8 ld8_str_clip(const float* p, int stride) {
    f16x8 r;
    #pragma unroll
    for (int j = 0; j < 8; ++j) r[j] = (_Float16)clp(p[j * stride]);
    return r;
}

// R19 = R18 structure (measured 82.9 us: weights-in-regs, padded act rows,
// 5 barriers) + heavy-ball solver.
//   Solver: x+ = x + a*r(x) + b*(x - x-), a=0.26 b=0.22 (see above). Always
//   evaluates at the ITERATE (unlike R17's Nesterov extrapolation, which
//   regressed 83.8->92.4 with beta=0.5 tuned for the wrong kappa). No big
//   early steps: R16's lamE=1.0 + 1/(it+2) floor amplified the L~7.7 top
//   mode for the first ~6 iters; we start at the known-stable step.
//   Safeguard: 3 consecutive norm growths => permanent fallback to the
//   proven R16 regime (beta=0, adaptive lam init 0.23, halve on growth).
// R14/R18 structure kept: 512-thread blocks (8 waves, 2/SIMD), 4 samples/
// block, forward M split over 8 waves, col phase duplicated across wave
// pairs, deferred sg2, weights+biases in registers.
__launch_bounds__(512, 1)
__global__ void blnn_kernel(const float* __restrict__ xin,
                            const float* __restrict__ Wy0,
                            const float* __restrict__ by0,
                            const float* __restrict__ Wy1,
                            const float* __restrict__ by1,
                            const float* __restrict__ Wz1,
                            const float* __restrict__ Wy2,
                            const float* __restrict__ by2,
                            const float* __restrict__ Wz2,
                            float* __restrict__ out)
{
    __shared__ __align__(16) _Float16 xact [4 * 80];   // x  per sample (pad 64->80)
    __shared__ __align__(16) _Float16 h0act[4 * 144];  // h0 per sample (pad 128->144)
    __shared__ __align__(16) _Float16 v1act[4 * 144];  // ~v1 (no sg2)
    __shared__ __align__(16) _Float16 v0act[4 * 144];
    __shared__ __align__(16) float hp[32];    // head partials [n4][w0..7]
    __shared__ __align__(16) float pxp[16];   // wy2.x partials [n4][cm]
    __shared__ __align__(16) float npar[16];  // norm^2 partials [n4][cm]

    const int tid  = threadIdx.x;
    const int w    = tid >> 6;        // 0..7
    const int cm   = w & 3;           // col-phase m-tile (pairs duplicate)
    const int l    = tid & 63;
    const int n    = l & 15;          // MFMA col
    const int n4   = n & 3;           // real sample
    const int quad = l >> 4;
    const int blk4 = blockIdx.x * 4;

    // ---- weights into REGISTERS (one-time; same frag order as R9 staging) ----
    const int rA = w * 16 + n;        // forward m-tile row, 0..127
    const int rT = cm * 16 + n;       // transposed row (c index), 0..63
    const int kq = quad * 8;

    f16x8 wa0[2], wa1[2];
    #pragma unroll
    for (int ks = 0; ks < 2; ++ks) {
        wa0[ks] = ld8(Wy0 + rA * 64 + ks * 32 + kq);
        wa1[ks] = ld8(Wy1 + rA * 64 + ks * 32 + kq);
    }
    f16x8 waz[4], wzt[4], w1t[4], w0t[4];
    #pragma unroll
    for (int ks = 0; ks < 4; ++ks) {
        waz[ks] = ld8_clip(Wz1 + rA * 128 + ks * 32 + kq);                 // Wz1+ row-major
        wzt[ks] = ld8_str_clip(Wz1 + (ks * 32 + kq) * 128 + rA, 128);      // Wz1+^T
        w1t[ks] = ld8_str(Wy1 + (ks * 32 + kq) * 64 + rT, 64);             // Wy1^T
        w0t[ks] = ld8_str(Wy0 + (ks * 32 + kq) * 64 + rT, 64);             // Wy0^T
    }
    const float4 bb0 = *(const float4*)(by0 + w * 16 + quad * 4);
    const float4 bb1 = *(const float4*)(by1 + w * 16 + quad * 4);
    float4 wzq;
    {
        const float4 t = *(const float4*)(Wz2 + w * 16 + quad * 4);
        wzq.x = clp(t.x); wzq.y = clp(t.y); wzq.z = clp(t.z); wzq.w = clp(t.w);
    }

    if (tid < 256) {   // x0 = z into act layout
        const int nn = tid >> 6, cc = tid & 63;
        xact[nn * 80 + cc] = (_Float16)xin[(blk4 + nn) * 64 + cc];
    }

    // ---- col-role state: rows c = cm*16 + quad*4 + r, sample n4 ----
    const float4 z4  = ((const float4*)xin)[(blk4 + n4) * 16 + cm * 4 + quad];
    const float4 wy4 = ((const float4*)Wy2)[cm * 4 + quad];
    float zr[4]   = {z4.x, z4.y, z4.z, z4.w};
    float wy2r[4] = {wy4.x, wy4.y, wy4.z, wy4.w};
    float xcur[4] = {zr[0], zr[1], zr[2], zr[3]};
    float xold[4] = {zr[0], zr[1], zr[2], zr[3]};   // heavy-ball x_{k-1}
    float prevn2 = 3.4e38f;
    float lamF   = 0.23f;    // fallback-mode adaptive step (R16 regime)
    int   bad    = 0;        // consecutive residual-growth count
    int   fbk    = 0;        // 0 = heavy-ball, 1 = fallback (permanent)
    const float b2 = by2[0];

    {   // px = sum_c wy2[c]*x[c] for first iteration
        float pxs = wy2r[0]*xcur[0] + wy2r[1]*xcur[1] + wy2r[2]*xcur[2] + wy2r[3]*xcur[3];
        pxs += __shfl_xor(pxs, 16, 64);
        pxs += __shfl_xor(pxs, 32, 64);
        if (w < 4 && l < 4) pxp[l * 4 + w] = pxs;
    }
    __syncthreads();

    const _Float16* xrow  = xact  + n4 * 80;
    const _Float16* h0row = h0act + n4 * 144;
    const _Float16* v1row = v1act + n4 * 144;
    const _Float16* v0row = v0act + n4 * 144;

    float sig0[4];

    for (int it = 0; it < MAX_IT; ++it) {
        // ---- P1: preact0 = Wy0 x + by0 -> h0, sig0 (m-tile w) ----
        f16x8 bx0 = *(const f16x8*)(xrow + quad * 8);
        f16x8 bx1 = *(const f16x8*)(xrow + 32 + quad * 8);
        {
            f32x4 acc = {0.f, 0.f, 0.f, 0.f};
            acc = MFMA(wa0[0], bx0, acc);
            acc = MFMA(wa0[1], bx1, acc);
            float sp0, sp1, sp2, sp3;
            sigsp(acc[0] + bb0.x, sig0[0], sp0);
            sigsp(acc[1] + bb0.y, sig0[1], sp1);
            sigsp(acc[2] + bb0.z, sig0[2], sp2);
            sigsp(acc[3] + bb0.w, sig0[3], sp3);
            if (n < 4)
                *(uint2*)&h0act[n4 * 144 + w * 16 + quad * 4] =
                    make_uint2(pack_h2(sp0, sp1), pack_h2(sp2, sp3));
        }
        __syncthreads();   // B1: h0 ready

        // ---- P2: preact1 -> sig1,h1 ; head partial ; ~v1 (m-tile w) ----
        f16x8 bh0 = *(const f16x8*)(h0row + quad * 8);
        f16x8 bh1 = *(const f16x8*)(h0row + 32 + quad * 8);
        f16x8 bh2 = *(const f16x8*)(h0row + 64 + quad * 8);
        f16x8 bh3 = *(const f16x8*)(h0row + 96 + quad * 8);
        float hsum = 0.0f;
        {
            f32x4 acc = {0.f, 0.f, 0.f, 0.f};
            acc = MFMA(waz[0], bh0, acc);
            acc = MFMA(waz[1], bh1, acc);
            acc = MFMA(waz[2], bh2, acc);
            acc = MFMA(waz[3], bh3, acc);
            acc = MFMA(wa1[0], bx0, acc);
            acc = MFMA(wa1[1], bx1, acc);
            float s1, h1;
            sigsp(acc[0] + bb1.x, s1, h1); hsum = fmaf(wzq.x, h1, hsum);
            const float t0 = s1 * wzq.x;
            sigsp(acc[1] + bb1.y, s1, h1); hsum = fmaf(wzq.y, h1, hsum);
            const float t1 = s1 * wzq.y;
            sigsp(acc[2] + bb1.z, s1, h1); hsum = fmaf(wzq.z, h1, hsum);
            const float t2 = s1 * wzq.z;
            sigsp(acc[3] + bb1.w, s1, h1); hsum = fmaf(wzq.w, h1, hsum);
            const float t3 = s1 * wzq.w;
            if (n < 4)
                *(uint2*)&v1act[n4 * 144 + w * 16 + quad * 4] =
                    make_uint2(pack_h2(t0, t1), pack_h2(t2, t3));
        }
        hsum += __shfl_xor(hsum, 16, 64);
        hsum += __shfl_xor(hsum, 32, 64);
        if (l < 4) hp[l * 8 + w] = hsum;   // hp[n4][w], 8 m-tiles
        __syncthreads();   // B2: hp AND ~v1 ready (sg2 deferred)

        // ---- P4: sg2; v0 = sig0*sg2*(Wz1+^T ~v1) (m-tile w); accg (cm) ----
        float sg2c;
        {
            const float4 h0v = ((const float4*)hp)[n4 * 2];
            const float4 h1v = ((const float4*)hp)[n4 * 2 + 1];
            const float4 pv  = ((const float4*)pxp)[n4];
            sg2c = sigm(h0v.x + h0v.y + h0v.z + h0v.w +
                        h1v.x + h1v.y + h1v.z + h1v.w +
                        pv.x + pv.y + pv.z + pv.w + b2);
        }
        f16x8 bv10 = *(const f16x8*)(v1row + quad * 8);
        f16x8 bv11 = *(const f16x8*)(v1row + 32 + quad * 8);
        f16x8 bv12 = *(const f16x8*)(v1row + 64 + quad * 8);
        f16x8 bv13 = *(const f16x8*)(v1row + 96 + quad * 8);
        {
            f32x4 acc = {0.f, 0.f, 0.f, 0.f};
            acc = MFMA(wzt[0], bv10, acc);
            acc = MFMA(wzt[1], bv11, acc);
            acc = MFMA(wzt[2], bv12, acc);
            acc = MFMA(wzt[3], bv13, acc);
            const float a0 = sig0[0] * sg2c * acc[0];
            const float a1 = sig0[1] * sg2c * acc[1];
            const float a2 = sig0[2] * sg2c * acc[2];
            const float a3 = sig0[3] * sg2c * acc[3];
            if (n < 4)
                *(uint2*)&v0act[n4 * 144 + w * 16 + quad * 4] =
                    make_uint2(pack_h2(a0, a1), pack_h2(a2, a3));
        }
        f32x4 accg = {0.f, 0.f, 0.f, 0.f};   // Wy1^T ~v1 (col m-tile cm)
        accg = MFMA(w1t[0], bv10, accg);
        accg = MFMA(w1t[1], bv11, accg);
        accg = MFMA(w1t[2], bv12, accg);
        accg = MFMA(w1t[3], bv13, accg);
        __syncthreads();   // B3: v0 ready

        // ---- P6: g = x + sg2*wy2 + sg2*accg + Wy0^T v0 ; residual norm ----
        f16x8 bv00 = *(const f16x8*)(v0row + quad * 8);
        f16x8 bv01 = *(const f16x8*)(v0row + 32 + quad * 8);
        f16x8 bv02 = *(const f16x8*)(v0row + 64 + quad * 8);
        f16x8 bv03 = *(const f16x8*)(v0row + 96 + quad * 8);
        f32x4 acc0 = {0.f, 0.f, 0.f, 0.f};
        acc0 = MFMA(w0t[0], bv00, acc0);
        acc0 = MFMA(w0t[1], bv01, acc0);
        acc0 = MFMA(w0t[2], bv02, acc0);
        acc0 = MFMA(w0t[3], bv03, acc0);
        float resid[4];
        float r2 = 0.0f;
        #pragma unroll
        for (int r = 0; r < 4; ++r) {
            const float g = xcur[r] + sg2c * wy2r[r] + sg2c * accg[r] + acc0[r];
            resid[r] = zr[r] - g;
            r2 = fmaf(resid[r], resid[r], r2);
        }
        r2 += __shfl_xor(r2, 16, 64);
        r2 += __shfl_xor(r2, 32, 64);
        if (w < 4 && l < 4) npar[l * 4 + w] = r2;   // npar[n4][cm]
        __syncthreads();   // B4: norm partials ready

        const float4 q0 = ((const float4*)npar)[0];
        const float4 q1 = ((const float4*)npar)[1];
        const float4 q2 = ((const float4*)npar)[2];
        const float4 q3 = ((const float4*)npar)[3];
        const float s0 = q0.x + q0.y + q0.z + q0.w;
        const float s1 = q1.x + q1.y + q1.z + q1.w;
        const float s2 = q2.x + q2.y + q2.z + q2.w;
        const float s3 = q3.x + q3.y + q3.z + q3.w;
        const float T2 = TOLF * TOLF;
        if (s0 < T2 && s1 < T2 && s2 < T2 && s3 < T2) break;   // uniform

        const float myn2 = (n4 == 0) ? s0 : (n4 == 1) ? s1 : (n4 == 2) ? s2 : s3;
        if (myn2 >= T2) {
            // growth tracking (shared by both modes)
            if (myn2 > prevn2 * 0.998f) { ++bad; } else { bad = 0; }
            if (!fbk && bad >= 3) { fbk = 1; bad = 0; }   // permanent fallback
            if (!fbk) {
                // heavy ball: x+ = x + a*r + b*(x - x-)
                #pragma unroll
                for (int r = 0; r < 4; ++r) {
                    const float xn = xcur[r] + ALPHA_HB * resid[r]
                                   + BETA_HB * (xcur[r] - xold[r]);
                    xold[r] = xcur[r];
                    xcur[r] = xn;
                }
            } else {
                // R16 adaptive Richardson (proven regime)
                if (bad > 0) lamF *= 0.5f;
                const float step = fmaxf(lamF, 0.02f);
                #pragma unroll
                for (int r = 0; r < 4; ++r) {
                    xold[r] = xcur[r];
                    xcur[r] = fmaf(step, resid[r], xcur[r]);
                }
            }
            prevn2 = myn2;
        }
        {   // px partial for next iter + x writeback
            float pxs = wy2r[0]*xcur[0] + wy2r[1]*xcur[1] + wy2r[2]*xcur[2] + wy2r[3]*xcur[3];
            pxs += __shfl_xor(pxs, 16, 64);
            pxs += __shfl_xor(pxs, 32, 64);
            if (w < 4 && l < 4) pxp[l * 4 + w] = pxs;
        }
        if (w < 4 && n < 4)
            *(uint2*)&xact[n4 * 80 + cm * 16 + quad * 4] =
                make_uint2(pack_h2(xcur[0], xcur[1]), pack_h2(xcur[2], xcur[3]));
        __syncthreads();   // B5: x ready
    }

    if (w < 4 && n < 4) {
        float4 o;
        o.x = xcur[0] + zr[0]; o.y = xcur[1] + zr[1];
        o.z = xcur[2] + zr[2]; o.w = xcur[3] + zr[3];
        ((float4*)out)[(blk4 + n4) * 16 + cm * 4 + quad] = o;   // + CONVEX*z
    }
}

extern "C" void kernel_launch(void* const* d_in, const int* in_sizes, int n_in,
                              void* d_out, int out_size, void* d_ws, size_t ws_size,
                              hipStream_t stream) {
    const float* xin = (const float*)d_in[0];
    const float* Wy0 = (const float*)d_in[1];
    const float* by0 = (const float*)d_in[2];
    const float* Wy1 = (const float*)d_in[3];
    const float* by1 = (const float*)d_in[4];
    const float* Wz1 = (const float*)d_in[5];
    const float* Wy2 = (const float*)d_in[6];
    const float* by2 = (const float*)d_in[7];
    const float* Wz2 = (const float*)d_in[8];
    float* out = (float*)d_out;

    blnn_kernel<<<dim3(NB / 4), dim3(512), 0, stream>>>(
        xin, Wy0, by0, Wy1, by1, Wz1, Wy2, by2, Wz2, out);
}

// Round 4
// 83.808 us; speedup vs baseline: 1.1923x; 1.1923x over previous
//
#include <hip/hip_runtime.h>
#include <math.h>

#define NB 1024   // batch
#define NC 64     // input dim
#define NH 128    // hidden dim
#define MAX_IT 500
#define TOLF 6e-3f   // ||r|| < TOL certifies ||x-x*|| < TOL (1-strong mono).

typedef _Float16 f16x8 __attribute__((ext_vector_type(8)));
typedef float    f32x4 __attribute__((ext_vector_type(4)));
typedef _Float16 h2    __attribute__((ext_vector_type(2)));

#define MFMA(a, b, c) __builtin_amdgcn_mfma_f32_16x16x32_f16((a), (b), (c), 0, 0, 0)

__device__ __forceinline__ unsigned pack_h2(float a, float b) {
    union { h2 h; unsigned u; } cv;
    cv.h.x = (_Float16)a; cv.h.y = (_Float16)b; return cv.u;
}
__device__ __forceinline__ float rcp_fast(float x) {
#if __has_builtin(__builtin_amdgcn_rcpf)
    return __builtin_amdgcn_rcpf(x);
#else
    return 1.0f / x;
#endif
}
// sigmoid + softplus sharing one exp
__device__ __forceinline__ void sigsp(float a, float& sig, float& sp) {
    const float e = __expf(-fabsf(a));
    const float r = rcp_fast(1.0f + e);
    sig = (a >= 0.0f) ? r : e * r;
    sp  = fmaxf(a, 0.0f) + __logf(1.0f + e);
}
__device__ __forceinline__ float sigm(float a) {
    const float e = __expf(-fabsf(a));
    const float r = rcp_fast(1.0f + e);
    return (a >= 0.0f) ? r : e * r;
}
__device__ __forceinline__ float clp(float x) { return fmaxf(x, 0.0f); }

// fragment loaders: 8 fp32 -> f16x8, same element order as the old LDS staging
__device__ __forceinline__ f16x8 ld8(const float* p) {
    const float4 a = ((const float4*)p)[0];
    const float4 b = ((const float4*)p)[1];
    f16x8 r;
    r[0]=(_Float16)a.x; r[1]=(_Float16)a.y; r[2]=(_Float16)a.z; r[3]=(_Float16)a.w;
    r[4]=(_Float16)b.x; r[5]=(_Float16)b.y; r[6]=(_Float16)b.z; r[7]=(_Float16)b.w;
    return r;
}
__device__ __forceinline__ f16x8 ld8_clip(const float* p) {
    const float4 a = ((const float4*)p)[0];
    const float4 b = ((const float4*)p)[1];
    f16x8 r;
    r[0]=(_Float16)clp(a.x); r[1]=(_Float16)clp(a.y); r[2]=(_Float16)clp(a.z); r[3]=(_Float16)clp(a.w);
    r[4]=(_Float16)clp(b.x); r[5]=(_Float16)clp(b.y); r[6]=(_Float16)clp(b.z); r[7]=(_Float16)clp(b.w);
    return r;
}
__device__ __forceinline__ f16x8 ld8_str(const float* p, int stride) {
    f16x8 r;
    #pragma unroll
    for (int j = 0; j < 8; ++j) r[j] = (_Float16)p[j * stride];
    return r;
}
__device__ __forceinline__ f16x8 ld8_str_clip(const float* p, int stride) {
    f16x8 r;
    #pragma unroll
    for (int j = 0; j < 8; ++j) r[j] = (_Float16)clp(p[j * stride]);
    return r;
}

// R20 = R18 structure (82.9 us: weights-in-regs, padded act rows, 5 barriers)
// + Barzilai-Borwein per-sample step. Evidence: per-iter cost ~0.23 us (R16's
// "7 tail iters" ~ 1.6 us, matches static estimate), so the worst block runs
// ~350 iterations -- iteration count of STIFF samples dominates. R17/R19's
// global fixed (alpha,beta) failed because per-sample local L is heterogeneous
// (some >> 8): fixed steps oscillate, fallbacks crawl at rho~0.98.
// BB1: with scalar updates x+ = x + lam*r, s = lam*r_prev, y = r_prev - r_now:
//   lam_new = <s,s>/<s,y> = lam * ||r_prev||^2 / (||r_prev||^2 - <r_prev,r_now>)
// Denominator = lam * r^T J r > 0 (J = Hessian of convex phi, PSD, mu>=1).
// Needs ONE extra cross-wave scalar <r_prev,r_now>, reduced exactly like the
// norm. Clamp lam in [0.004, 1.0], growth cap 8x/step, first step 0.23.
// Frozen samples (||r||<TOL) skip updates; (rprev,prevn2,lam) always refer to
// the last APPLIED step, so the BB pair stays consistent across freezes.
// R14/R18 structure kept: 512 threads (8 waves, 2/SIMD), 4 samples/block,
// forward M split over 8 waves, col phase duplicated across wave pairs,
// deferred sg2, weights+biases in registers, 5 barriers.
__launch_bounds__(512, 1)
__global__ void blnn_kernel(const float* __restrict__ xin,
                            const float* __restrict__ Wy0,
                            const float* __restrict__ by0,
                            const float* __restrict__ Wy1,
                            const float* __restrict__ by1,
                            const float* __restrict__ Wz1,
                            const float* __restrict__ Wy2,
                            const float* __restrict__ by2,
                            const float* __restrict__ Wz2,
                            float* __restrict__ out)
{
    __shared__ __align__(16) _Float16 xact [4 * 80];   // x  per sample (pad 64->80)
    __shared__ __align__(16) _Float16 h0act[4 * 144];  // h0 per sample (pad 128->144)
    __shared__ __align__(16) _Float16 v1act[4 * 144];  // ~v1 (no sg2)
    __shared__ __align__(16) _Float16 v0act[4 * 144];
    __shared__ __align__(16) float hp[32];    // head partials [n4][w0..7]
    __shared__ __align__(16) float pxp[16];   // wy2.x partials [n4][cm]
    __shared__ __align__(16) float npar[16];  // norm^2 partials [n4][cm]
    __shared__ __align__(16) float dpar[16];  // <r_prev,r_now> partials [n4][cm]

    const int tid  = threadIdx.x;
    const int w    = tid >> 6;        // 0..7
    const int cm   = w & 3;           // col-phase m-tile (pairs duplicate)
    const int l    = tid & 63;
    const int n    = l & 15;          // MFMA col
    const int n4   = n & 3;           // real sample
    const int quad = l >> 4;
    const int blk4 = blockIdx.x * 4;

    // ---- weights into REGISTERS (one-time; same frag order as R9 staging) ----
    const int rA = w * 16 + n;        // forward m-tile row, 0..127
    const int rT = cm * 16 + n;       // transposed row (c index), 0..63
    const int kq = quad * 8;

    f16x8 wa0[2], wa1[2];
    #pragma unroll
    for (int ks = 0; ks < 2; ++ks) {
        wa0[ks] = ld8(Wy0 + rA * 64 + ks * 32 + kq);
        wa1[ks] = ld8(Wy1 + rA * 64 + ks * 32 + kq);
    }
    f16x8 waz[4], wzt[4], w1t[4], w0t[4];
    #pragma unroll
    for (int ks = 0; ks < 4; ++ks) {
        waz[ks] = ld8_clip(Wz1 + rA * 128 + ks * 32 + kq);                 // Wz1+ row-major
        wzt[ks] = ld8_str_clip(Wz1 + (ks * 32 + kq) * 128 + rA, 128);      // Wz1+^T
        w1t[ks] = ld8_str(Wy1 + (ks * 32 + kq) * 64 + rT, 64);             // Wy1^T
        w0t[ks] = ld8_str(Wy0 + (ks * 32 + kq) * 64 + rT, 64);             // Wy0^T
    }
    const float4 bb0 = *(const float4*)(by0 + w * 16 + quad * 4);
    const float4 bb1 = *(const float4*)(by1 + w * 16 + quad * 4);
    float4 wzq;
    {
        const float4 t = *(const float4*)(Wz2 + w * 16 + quad * 4);
        wzq.x = clp(t.x); wzq.y = clp(t.y); wzq.z = clp(t.z); wzq.w = clp(t.w);
    }

    if (tid < 256) {   // x0 = z into act layout
        const int nn = tid >> 6, cc = tid & 63;
        xact[nn * 80 + cc] = (_Float16)xin[(blk4 + nn) * 64 + cc];
    }

    // ---- col-role state: rows c = cm*16 + quad*4 + r, sample n4 ----
    const float4 z4  = ((const float4*)xin)[(blk4 + n4) * 16 + cm * 4 + quad];
    const float4 wy4 = ((const float4*)Wy2)[cm * 4 + quad];
    float zr[4]   = {z4.x, z4.y, z4.z, z4.w};
    float wy2r[4] = {wy4.x, wy4.y, wy4.z, wy4.w};
    float xcur[4] = {zr[0], zr[1], zr[2], zr[3]};
    float rprev[4] = {0.f, 0.f, 0.f, 0.f};   // residual at last APPLIED step
    float prevn2 = 3.4e38f;                  // ||rprev||^2 at last applied step
    float lamE   = -1.0f;                    // <0: no prior step (use 0.23)
    const float b2 = by2[0];

    {   // px = sum_c wy2[c]*x[c] for first iteration
        float pxs = wy2r[0]*xcur[0] + wy2r[1]*xcur[1] + wy2r[2]*xcur[2] + wy2r[3]*xcur[3];
        pxs += __shfl_xor(pxs, 16, 64);
        pxs += __shfl_xor(pxs, 32, 64);
        if (w < 4 && l < 4) pxp[l * 4 + w] = pxs;
    }
    __syncthreads();

    const _Float16* xrow  = xact  + n4 * 80;
    const _Float16* h0row = h0act + n4 * 144;
    const _Float16* v1row = v1act + n4 * 144;
    const _Float16* v0row = v0act + n4 * 144;

    float sig0[4];

    for (int it = 0; it < MAX_IT; ++it) {
        // ---- P1: preact0 = Wy0 x + by0 -> h0, sig0 (m-tile w) ----
        f16x8 bx0 = *(const f16x8*)(xrow + quad * 8);
        f16x8 bx1 = *(const f16x8*)(xrow + 32 + quad * 8);
        {
            f32x4 acc = {0.f, 0.f, 0.f, 0.f};
            acc = MFMA(wa0[0], bx0, acc);
            acc = MFMA(wa0[1], bx1, acc);
            float sp0, sp1, sp2, sp3;
            sigsp(acc[0] + bb0.x, sig0[0], sp0);
            sigsp(acc[1] + bb0.y, sig0[1], sp1);
            sigsp(acc[2] + bb0.z, sig0[2], sp2);
            sigsp(acc[3] + bb0.w, sig0[3], sp3);
            if (n < 4)
                *(uint2*)&h0act[n4 * 144 + w * 16 + quad * 4] =
                    make_uint2(pack_h2(sp0, sp1), pack_h2(sp2, sp3));
        }
        __syncthreads();   // B1: h0 ready

        // ---- P2: preact1 -> sig1,h1 ; head partial ; ~v1 (m-tile w) ----
        f16x8 bh0 = *(const f16x8*)(h0row + quad * 8);
        f16x8 bh1 = *(const f16x8*)(h0row + 32 + quad * 8);
        f16x8 bh2 = *(const f16x8*)(h0row + 64 + quad * 8);
        f16x8 bh3 = *(const f16x8*)(h0row + 96 + quad * 8);
        float hsum = 0.0f;
        {
            f32x4 acc = {0.f, 0.f, 0.f, 0.f};
            acc = MFMA(waz[0], bh0, acc);
            acc = MFMA(waz[1], bh1, acc);
            acc = MFMA(waz[2], bh2, acc);
            acc = MFMA(waz[3], bh3, acc);
            acc = MFMA(wa1[0], bx0, acc);
            acc = MFMA(wa1[1], bx1, acc);
            float s1, h1;
            sigsp(acc[0] + bb1.x, s1, h1); hsum = fmaf(wzq.x, h1, hsum);
            const float t0 = s1 * wzq.x;
            sigsp(acc[1] + bb1.y, s1, h1); hsum = fmaf(wzq.y, h1, hsum);
            const float t1 = s1 * wzq.y;
            sigsp(acc[2] + bb1.z, s1, h1); hsum = fmaf(wzq.z, h1, hsum);
            const float t2 = s1 * wzq.z;
            sigsp(acc[3] + bb1.w, s1, h1); hsum = fmaf(wzq.w, h1, hsum);
            const float t3 = s1 * wzq.w;
            if (n < 4)
                *(uint2*)&v1act[n4 * 144 + w * 16 + quad * 4] =
                    make_uint2(pack_h2(t0, t1), pack_h2(t2, t3));
        }
        hsum += __shfl_xor(hsum, 16, 64);
        hsum += __shfl_xor(hsum, 32, 64);
        if (l < 4) hp[l * 8 + w] = hsum;   // hp[n4][w], 8 m-tiles
        __syncthreads();   // B2: hp AND ~v1 ready (sg2 deferred)

        // ---- P4: sg2; v0 = sig0*sg2*(Wz1+^T ~v1) (m-tile w); accg (cm) ----
        float sg2c;
        {
            const float4 h0v = ((const float4*)hp)[n4 * 2];
            const float4 h1v = ((const float4*)hp)[n4 * 2 + 1];
            const float4 pv  = ((const float4*)pxp)[n4];
            sg2c = sigm(h0v.x + h0v.y + h0v.z + h0v.w +
                        h1v.x + h1v.y + h1v.z + h1v.w +
                        pv.x + pv.y + pv.z + pv.w + b2);
        }
        f16x8 bv10 = *(const f16x8*)(v1row + quad * 8);
        f16x8 bv11 = *(const f16x8*)(v1row + 32 + quad * 8);
        f16x8 bv12 = *(const f16x8*)(v1row + 64 + quad * 8);
        f16x8 bv13 = *(const f16x8*)(v1row + 96 + quad * 8);
        {
            f32x4 acc = {0.f, 0.f, 0.f, 0.f};
            acc = MFMA(wzt[0], bv10, acc);
            acc = MFMA(wzt[1], bv11, acc);
            acc = MFMA(wzt[2], bv12, acc);
            acc = MFMA(wzt[3], bv13, acc);
            const float a0 = sig0[0] * sg2c * acc[0];
            const float a1 = sig0[1] * sg2c * acc[1];
            const float a2 = sig0[2] * sg2c * acc[2];
            const float a3 = sig0[3] * sg2c * acc[3];
            if (n < 4)
                *(uint2*)&v0act[n4 * 144 + w * 16 + quad * 4] =
                    make_uint2(pack_h2(a0, a1), pack_h2(a2, a3));
        }
        f32x4 accg = {0.f, 0.f, 0.f, 0.f};   // Wy1^T ~v1 (col m-tile cm)
        accg = MFMA(w1t[0], bv10, accg);
        accg = MFMA(w1t[1], bv11, accg);
        accg = MFMA(w1t[2], bv12, accg);
        accg = MFMA(w1t[3], bv13, accg);
        __syncthreads();   // B3: v0 ready

        // ---- P6: g = x + sg2*wy2 + sg2*accg + Wy0^T v0 ; residual norm+dot ----
        f16x8 bv00 = *(const f16x8*)(v0row + quad * 8);
        f16x8 bv01 = *(const f16x8*)(v0row + 32 + quad * 8);
        f16x8 bv02 = *(const f16x8*)(v0row + 64 + quad * 8);
        f16x8 bv03 = *(const f16x8*)(v0row + 96 + quad * 8);
        f32x4 acc0 = {0.f, 0.f, 0.f, 0.f};
        acc0 = MFMA(w0t[0], bv00, acc0);
        acc0 = MFMA(w0t[1], bv01, acc0);
        acc0 = MFMA(w0t[2], bv02, acc0);
        acc0 = MFMA(w0t[3], bv03, acc0);
        float resid[4];
        float r2 = 0.0f, dp = 0.0f;
        #pragma unroll
        for (int r = 0; r < 4; ++r) {
            const float g = xcur[r] + sg2c * wy2r[r] + sg2c * accg[r] + acc0[r];
            resid[r] = zr[r] - g;
            r2 = fmaf(resid[r], resid[r], r2);
            dp = fmaf(rprev[r], resid[r], dp);
        }
        r2 += __shfl_xor(r2, 16, 64);
        r2 += __shfl_xor(r2, 32, 64);
        dp += __shfl_xor(dp, 16, 64);
        dp += __shfl_xor(dp, 32, 64);
        if (w < 4 && l < 4) { npar[l * 4 + w] = r2; dpar[l * 4 + w] = dp; }
        __syncthreads();   // B4: norm/dot partials ready

        const float4 q0 = ((const float4*)npar)[0];
        const float4 q1 = ((const float4*)npar)[1];
        const float4 q2 = ((const float4*)npar)[2];
        const float4 q3 = ((const float4*)npar)[3];
        const float s0 = q0.x + q0.y + q0.z + q0.w;
        const float s1 = q1.x + q1.y + q1.z + q1.w;
        const float s2 = q2.x + q2.y + q2.z + q2.w;
        const float s3 = q3.x + q3.y + q3.z + q3.w;
        const float T2 = TOLF * TOLF;
        if (s0 < T2 && s1 < T2 && s2 < T2 && s3 < T2) break;   // uniform

        const float myn2 = (n4 == 0) ? s0 : (n4 == 1) ? s1 : (n4 == 2) ? s2 : s3;
        if (myn2 >= T2) {
            float lamN;
            if (lamE < 0.0f) {
                lamN = 0.23f;                       // first step: known-stable
            } else {
                const float4 qd = ((const float4*)dpar)[n4];
                const float mydot = qd.x + qd.y + qd.z + qd.w;
                const float den = prevn2 - mydot;   // = lam * r^T J r > 0 (PSD)
                lamN = lamE * prevn2 / den;         // BB1
                const float cap = fminf(1.0f, 8.0f * lamE);   // growth cap
                if (!(lamN > 0.004f)) lamN = 0.004f;          // also catches NaN
                if (lamN > cap) lamN = cap;
            }
            #pragma unroll
            for (int r = 0; r < 4; ++r) {
                rprev[r] = resid[r];
                xcur[r]  = fmaf(lamN, resid[r], xcur[r]);
            }
            lamE = lamN;
            prevn2 = myn2;
        }
        {   // px partial for next iter + x writeback
            float pxs = wy2r[0]*xcur[0] + wy2r[1]*xcur[1] + wy2r[2]*xcur[2] + wy2r[3]*xcur[3];
            pxs += __shfl_xor(pxs, 16, 64);
            pxs += __shfl_xor(pxs, 32, 64);
            if (w < 4 && l < 4) pxp[l * 4 + w] = pxs;
        }
        if (w < 4 && n < 4)
            *(uint2*)&xact[n4 * 80 + cm * 16 + quad * 4] =
                make_uint2(pack_h2(xcur[0], xcur[1]), pack_h2(xcur[2], xcur[3]));
        __syncthreads();   // B5: x ready
    }

    if (w < 4 && n < 4) {
        float4 o;
        o.x = xcur[0] + zr[0]; o.y = xcur[1] + zr[1];
        o.z = xcur[2] + zr[2]; o.w = xcur[3] + zr[3];
        ((float4*)out)[(blk4 + n4) * 16 + cm * 4 + quad] = o;   // + CONVEX*z
    }
}

extern "C" void kernel_launch(void* const* d_in, const int* in_sizes, int n_in,
                              void* d_out, int out_size, void* d_ws, size_t ws_size,
                              hipStream_t stream) {
    const float* xin = (const float*)d_in[0];
    const float* Wy0 = (const float*)d_in[1];
    const float* by0 = (const float*)d_in[2];
    const float* Wy1 = (const float*)d_in[3];
    const float* by1 = (const float*)d_in[4];
    const float* Wz1 = (const float*)d_in[5];
    const float* Wy2 = (const float*)d_in[6];
    const float* by2 = (const float*)d_in[7];
    const float* Wz2 = (const float*)d_in[8];
    float* out = (float*)d_out;

    blnn_kernel<<<dim3(NB / 4), dim3(512), 0, stream>>>(
        xin, Wy0, by0, Wy1, by1, Wz1, Wy2, by2, Wz2, out);
}

// Round 5
// 83.259 us; speedup vs baseline: 1.2001x; 1.0066x over previous
//
#include <hip/hip_runtime.h>
#include <math.h>

#define NB 1024   // batch
#define NC 64     // input dim
#define NH 128    // hidden dim
#define MAX_IT 200   // R21: cut from 500. Evidence (R16-R20): duration scales
                     // with per-iter VALU cost, NOT solver quality (BB per-
                     // sample adaptive = neutral; TOLF 6x = ~neutral; absmax
                     // pinned at 0.03125 = fp16-floor signature). => worst
                     // sample(s) plateau above TOLF and the loop runs the
                     // FULL cap; iters 200..500 were dead time. Clean samples
                     // (rho<=0.93) are < 1e-4 by it~130; floored samples gain
                     // nothing past ~150. t_iter ~= 0.167 us => predict ~34 us.
#define TOLF 6e-3f   // ||r|| < TOL certifies ||x-x*|| < TOL (1-strong mono).

typedef _Float16 f16x8 __attribute__((ext_vector_type(8)));
typedef float    f32x4 __attribute__((ext_vector_type(4)));
typedef _Float16 h2    __attribute__((ext_vector_type(2)));

#define MFMA(a, b, c) __builtin_amdgcn_mfma_f32_16x16x32_f16((a), (b), (c), 0, 0, 0)

__device__ __forceinline__ unsigned pack_h2(float a, float b) {
    union { h2 h; unsigned u; } cv;
    cv.h.x = (_Float16)a; cv.h.y = (_Float16)b; return cv.u;
}
__device__ __forceinline__ float rcp_fast(float x) {
#if __has_builtin(__builtin_amdgcn_rcpf)
    return __builtin_amdgcn_rcpf(x);
#else
    return 1.0f / x;
#endif
}
// sigmoid + softplus sharing one exp
__device__ __forceinline__ void sigsp(float a, float& sig, float& sp) {
    const float e = __expf(-fabsf(a));
    const float r = rcp_fast(1.0f + e);
    sig = (a >= 0.0f) ? r : e * r;
    sp  = fmaxf(a, 0.0f) + __logf(1.0f + e);
}
__device__ __forceinline__ float sigm(float a) {
    const float e = __expf(-fabsf(a));
    const float r = rcp_fast(1.0f + e);
    return (a >= 0.0f) ? r : e * r;
}
__device__ __forceinline__ float clp(float x) { return fmaxf(x, 0.0f); }

// fragment loaders: 8 fp32 -> f16x8, same element order as the old LDS staging
__device__ __forceinline__ f16x8 ld8(const float* p) {
    const float4 a = ((const float4*)p)[0];
    const float4 b = ((const float4*)p)[1];
    f16x8 r;
    r[0]=(_Float16)a.x; r[1]=(_Float16)a.y; r[2]=(_Float16)a.z; r[3]=(_Float16)a.w;
    r[4]=(_Float16)b.x; r[5]=(_Float16)b.y; r[6]=(_Float16)b.z; r[7]=(_Float16)b.w;
    return r;
}
__device__ __forceinline__ f16x8 ld8_clip(const float* p) {
    const float4 a = ((const float4*)p)[0];
    const float4 b = ((const float4*)p)[1];
    f16x8 r;
    r[0]=(_Float16)clp(a.x); r[1]=(_Float16)clp(a.y); r[2]=(_Float16)clp(a.z); r[3]=(_Float16)clp(a.w);
    r[4]=(_Float16)clp(b.x); r[5]=(_Float16)clp(b.y); r[6]=(_Float16)clp(b.z); r[7]=(_Float16)clp(b.w);
    return r;
}
__device__ __forceinline__ f16x8 ld8_str(const float* p, int stride) {
    f16x8 r;
    #pragma unroll
    for (int j = 0; j < 8; ++j) r[j] = (_Float16)p[j * stride];
    return r;
}
__device__ __forceinline__ f16x8 ld8_str_clip(const float* p, int stride) {
    f16x8 r;
    #pragma unroll
    for (int j = 0; j < 8; ++j) r[j] = (_Float16)clp(p[j * stride]);
    return r;
}

// R21 = R18 (measured 82.9 us: weights-in-regs, padded act rows, 5 barriers,
// R3 adaptive-Richardson solver — the leanest per-iteration variant) with
// MAX_IT 500 -> 200. BB machinery (R20, neutral) reverted to keep per-iter
// cost minimal, since per-iter cost is what duration scales with.
// Break kept: free insurance if all samples do converge early.
__launch_bounds__(512, 1)
__global__ void blnn_kernel(const float* __restrict__ xin,
                            const float* __restrict__ Wy0,
                            const float* __restrict__ by0,
                            const float* __restrict__ Wy1,
                            const float* __restrict__ by1,
                            const float* __restrict__ Wz1,
                            const float* __restrict__ Wy2,
                            const float* __restrict__ by2,
                            const float* __restrict__ Wz2,
                            float* __restrict__ out)
{
    __shared__ __align__(16) _Float16 xact [4 * 80];   // x  per sample (pad 64->80)
    __shared__ __align__(16) _Float16 h0act[4 * 144];  // h0 per sample (pad 128->144)
    __shared__ __align__(16) _Float16 v1act[4 * 144];  // ~v1 (no sg2)
    __shared__ __align__(16) _Float16 v0act[4 * 144];
    __shared__ __align__(16) float hp[32];    // head partials [n4][w0..7]
    __shared__ __align__(16) float pxp[16];   // wy2.x partials [n4][cm]
    __shared__ __align__(16) float npar[16];  // norm^2 partials [n4][cm]

    const int tid  = threadIdx.x;
    const int w    = tid >> 6;        // 0..7
    const int cm   = w & 3;           // col-phase m-tile (pairs duplicate)
    const int l    = tid & 63;
    const int n    = l & 15;          // MFMA col
    const int n4   = n & 3;           // real sample
    const int quad = l >> 4;
    const int blk4 = blockIdx.x * 4;

    // ---- weights into REGISTERS (one-time; same frag order as R9 staging) ----
    const int rA = w * 16 + n;        // forward m-tile row, 0..127
    const int rT = cm * 16 + n;       // transposed row (c index), 0..63
    const int kq = quad * 8;

    f16x8 wa0[2], wa1[2];
    #pragma unroll
    for (int ks = 0; ks < 2; ++ks) {
        wa0[ks] = ld8(Wy0 + rA * 64 + ks * 32 + kq);
        wa1[ks] = ld8(Wy1 + rA * 64 + ks * 32 + kq);
    }
    f16x8 waz[4], wzt[4], w1t[4], w0t[4];
    #pragma unroll
    for (int ks = 0; ks < 4; ++ks) {
        waz[ks] = ld8_clip(Wz1 + rA * 128 + ks * 32 + kq);                 // Wz1+ row-major
        wzt[ks] = ld8_str_clip(Wz1 + (ks * 32 + kq) * 128 + rA, 128);      // Wz1+^T
        w1t[ks] = ld8_str(Wy1 + (ks * 32 + kq) * 64 + rT, 64);             // Wy1^T
        w0t[ks] = ld8_str(Wy0 + (ks * 32 + kq) * 64 + rT, 64);             // Wy0^T
    }
    const float4 bb0 = *(const float4*)(by0 + w * 16 + quad * 4);
    const float4 bb1 = *(const float4*)(by1 + w * 16 + quad * 4);
    float4 wzq;
    {
        const float4 t = *(const float4*)(Wz2 + w * 16 + quad * 4);
        wzq.x = clp(t.x); wzq.y = clp(t.y); wzq.z = clp(t.z); wzq.w = clp(t.w);
    }

    if (tid < 256) {   // x0 = z into act layout
        const int nn = tid >> 6, cc = tid & 63;
        xact[nn * 80 + cc] = (_Float16)xin[(blk4 + nn) * 64 + cc];
    }

    // ---- col-role state: rows c = cm*16 + quad*4 + r, sample n4 ----
    const float4 z4  = ((const float4*)xin)[(blk4 + n4) * 16 + cm * 4 + quad];
    const float4 wy4 = ((const float4*)Wy2)[cm * 4 + quad];
    float zr[4]   = {z4.x, z4.y, z4.z, z4.w};
    float wy2r[4] = {wy4.x, wy4.y, wy4.z, wy4.w};
    float xcur[4] = {zr[0], zr[1], zr[2], zr[3]};
    float lamE = 1.0f, prevn2 = 3.4e38f;
    const float b2 = by2[0];

    {   // px = sum_c wy2[c]*x[c] for first iteration
        float pxs = wy2r[0]*xcur[0] + wy2r[1]*xcur[1] + wy2r[2]*xcur[2] + wy2r[3]*xcur[3];
        pxs += __shfl_xor(pxs, 16, 64);
        pxs += __shfl_xor(pxs, 32, 64);
        if (w < 4 && l < 4) pxp[l * 4 + w] = pxs;
    }
    __syncthreads();

    const _Float16* xrow  = xact  + n4 * 80;
    const _Float16* h0row = h0act + n4 * 144;
    const _Float16* v1row = v1act + n4 * 144;
    const _Float16* v0row = v0act + n4 * 144;

    float sig0[4];

    for (int it = 0; it < MAX_IT; ++it) {
        // ---- P1: preact0 = Wy0 x + by0 -> h0, sig0 (m-tile w) ----
        f16x8 bx0 = *(const f16x8*)(xrow + quad * 8);
        f16x8 bx1 = *(const f16x8*)(xrow + 32 + quad * 8);
        {
            f32x4 acc = {0.f, 0.f, 0.f, 0.f};
            acc = MFMA(wa0[0], bx0, acc);
            acc = MFMA(wa0[1], bx1, acc);
            float sp0, sp1, sp2, sp3;
            sigsp(acc[0] + bb0.x, sig0[0], sp0);
            sigsp(acc[1] + bb0.y, sig0[1], sp1);
            sigsp(acc[2] + bb0.z, sig0[2], sp2);
            sigsp(acc[3] + bb0.w, sig0[3], sp3);
            if (n < 4)
                *(uint2*)&h0act[n4 * 144 + w * 16 + quad * 4] =
                    make_uint2(pack_h2(sp0, sp1), pack_h2(sp2, sp3));
        }
        __syncthreads();   // B1: h0 ready

        // ---- P2: preact1 -> sig1,h1 ; head partial ; ~v1 (m-tile w) ----
        f16x8 bh0 = *(const f16x8*)(h0row + quad * 8);
        f16x8 bh1 = *(const f16x8*)(h0row + 32 + quad * 8);
        f16x8 bh2 = *(const f16x8*)(h0row + 64 + quad * 8);
        f16x8 bh3 = *(const f16x8*)(h0row + 96 + quad * 8);
        float hsum = 0.0f;
        {
            f32x4 acc = {0.f, 0.f, 0.f, 0.f};
            acc = MFMA(waz[0], bh0, acc);
            acc = MFMA(waz[1], bh1, acc);
            acc = MFMA(waz[2], bh2, acc);
            acc = MFMA(waz[3], bh3, acc);
            acc = MFMA(wa1[0], bx0, acc);
            acc = MFMA(wa1[1], bx1, acc);
            float s1, h1;
            sigsp(acc[0] + bb1.x, s1, h1); hsum = fmaf(wzq.x, h1, hsum);
            const float t0 = s1 * wzq.x;
            sigsp(acc[1] + bb1.y, s1, h1); hsum = fmaf(wzq.y, h1, hsum);
            const float t1 = s1 * wzq.y;
            sigsp(acc[2] + bb1.z, s1, h1); hsum = fmaf(wzq.z, h1, hsum);
            const float t2 = s1 * wzq.z;
            sigsp(acc[3] + bb1.w, s1, h1); hsum = fmaf(wzq.w, h1, hsum);
            const float t3 = s1 * wzq.w;
            if (n < 4)
                *(uint2*)&v1act[n4 * 144 + w * 16 + quad * 4] =
                    make_uint2(pack_h2(t0, t1), pack_h2(t2, t3));
        }
        hsum += __shfl_xor(hsum, 16, 64);
        hsum += __shfl_xor(hsum, 32, 64);
        if (l < 4) hp[l * 8 + w] = hsum;   // hp[n4][w], 8 m-tiles
        __syncthreads();   // B2: hp AND ~v1 ready (sg2 deferred)

        // ---- P4: sg2; v0 = sig0*sg2*(Wz1+^T ~v1) (m-tile w); accg (cm) ----
        float sg2c;
        {
            const float4 h0v = ((const float4*)hp)[n4 * 2];
            const float4 h1v = ((const float4*)hp)[n4 * 2 + 1];
            const float4 pv  = ((const float4*)pxp)[n4];
            sg2c = sigm(h0v.x + h0v.y + h0v.z + h0v.w +
                        h1v.x + h1v.y + h1v.z + h1v.w +
                        pv.x + pv.y + pv.z + pv.w + b2);
        }
        f16x8 bv10 = *(const f16x8*)(v1row + quad * 8);
        f16x8 bv11 = *(const f16x8*)(v1row + 32 + quad * 8);
        f16x8 bv12 = *(const f16x8*)(v1row + 64 + quad * 8);
        f16x8 bv13 = *(const f16x8*)(v1row + 96 + quad * 8);
        {
            f32x4 acc = {0.f, 0.f, 0.f, 0.f};
            acc = MFMA(wzt[0], bv10, acc);
            acc = MFMA(wzt[1], bv11, acc);
            acc = MFMA(wzt[2], bv12, acc);
            acc = MFMA(wzt[3], bv13, acc);
            const float a0 = sig0[0] * sg2c * acc[0];
            const float a1 = sig0[1] * sg2c * acc[1];
            const float a2 = sig0[2] * sg2c * acc[2];
            const float a3 = sig0[3] * sg2c * acc[3];
            if (n < 4)
                *(uint2*)&v0act[n4 * 144 + w * 16 + quad * 4] =
                    make_uint2(pack_h2(a0, a1), pack_h2(a2, a3));
        }
        f32x4 accg = {0.f, 0.f, 0.f, 0.f};   // Wy1^T ~v1 (col m-tile cm)
        accg = MFMA(w1t[0], bv10, accg);
        accg = MFMA(w1t[1], bv11, accg);
        accg = MFMA(w1t[2], bv12, accg);
        accg = MFMA(w1t[3], bv13, accg);
        __syncthreads();   // B3: v0 ready

        // ---- P6: g = x + sg2*wy2 + sg2*accg + Wy0^T v0 ; residual norm ----
        f16x8 bv00 = *(const f16x8*)(v0row + quad * 8);
        f16x8 bv01 = *(const f16x8*)(v0row + 32 + quad * 8);
        f16x8 bv02 = *(const f16x8*)(v0row + 64 + quad * 8);
        f16x8 bv03 = *(const f16x8*)(v0row + 96 + quad * 8);
        f32x4 acc0 = {0.f, 0.f, 0.f, 0.f};
        acc0 = MFMA(w0t[0], bv00, acc0);
        acc0 = MFMA(w0t[1], bv01, acc0);
        acc0 = MFMA(w0t[2], bv02, acc0);
        acc0 = MFMA(w0t[3], bv03, acc0);
        float resid[4];
        float r2 = 0.0f;
        #pragma unroll
        for (int r = 0; r < 4; ++r) {
            const float g = xcur[r] + sg2c * wy2r[r] + sg2c * accg[r] + acc0[r];
            resid[r] = zr[r] - g;
            r2 = fmaf(resid[r], resid[r], r2);
        }
        r2 += __shfl_xor(r2, 16, 64);
        r2 += __shfl_xor(r2, 32, 64);
        if (w < 4 && l < 4) npar[l * 4 + w] = r2;   // npar[n4][cm]
        __syncthreads();   // B4: norm partials ready

        const float4 q0 = ((const float4*)npar)[0];
        const float4 q1 = ((const float4*)npar)[1];
        const float4 q2 = ((const float4*)npar)[2];
        const float4 q3 = ((const float4*)npar)[3];
        const float s0 = q0.x + q0.y + q0.z + q0.w;
        const float s1 = q1.x + q1.y + q1.z + q1.w;
        const float s2 = q2.x + q2.y + q2.z + q2.w;
        const float s3 = q3.x + q3.y + q3.z + q3.w;
        const float T2 = TOLF * TOLF;
        if (s0 < T2 && s1 < T2 && s2 < T2 && s3 < T2) break;   // uniform

        const float myn2 = (n4 == 0) ? s0 : (n4 == 1) ? s1 : (n4 == 2) ? s2 : s3;
        if (myn2 >= T2) {                    // adaptive Richardson (R3 solver)
            if (myn2 > prevn2 * 0.998f) lamE *= 0.5f;
            const float step = fmaxf(lamE, 1.0f / (float)(it + 2));
            #pragma unroll
            for (int r = 0; r < 4; ++r) xcur[r] = fmaf(step, resid[r], xcur[r]);
            prevn2 = myn2;
        }
        {   // px partial for next iter + x writeback
            float pxs = wy2r[0]*xcur[0] + wy2r[1]*xcur[1] + wy2r[2]*xcur[2] + wy2r[3]*xcur[3];
            pxs += __shfl_xor(pxs, 16, 64);
            pxs += __shfl_xor(pxs, 32, 64);
            if (w < 4 && l < 4) pxp[l * 4 + w] = pxs;
        }
        if (w < 4 && n < 4)
            *(uint2*)&xact[n4 * 80 + cm * 16 + quad * 4] =
                make_uint2(pack_h2(xcur[0], xcur[1]), pack_h2(xcur[2], xcur[3]));
        __syncthreads();   // B5: x ready
    }

    if (w < 4 && n < 4) {
        float4 o;
        o.x = xcur[0] + zr[0]; o.y = xcur[1] + zr[1];
        o.z = xcur[2] + zr[2]; o.w = xcur[3] + zr[3];
        ((float4*)out)[(blk4 + n4) * 16 + cm * 4 + quad] = o;   // + CONVEX*z
    }
}

extern "C" void kernel_launch(void* const* d_in, const int* in_sizes, int n_in,
                              void* d_out, int out_size, void* d_ws, size_t ws_size,
                              hipStream_t stream) {
    const float* xin = (const float*)d_in[0];
    const float* Wy0 = (const float*)d_in[1];
    const float* by0 = (const float*)d_in[2];
    const float* Wy1 = (const float*)d_in[3];
    const float* by1 = (const float*)d_in[4];
    const float* Wz1 = (const float*)d_in[5];
    const float* Wy2 = (const float*)d_in[6];
    const float* by2 = (const float*)d_in[7];
    const float* Wz2 = (const float*)d_in[8];
    float* out = (float*)d_out;

    blnn_kernel<<<dim3(NB / 4), dim3(512), 0, stream>>>(
        xin, Wy0, by0, Wy1, by1, Wz1, Wy2, by2, Wz2, out);
}